// Round 1
// baseline (10975.210 us; speedup 1.0000x reference)
//
#include <hip/hip_runtime.h>
#include <hip/hip_bf16.h>

// LSTM layer: T=512, B=64, D=1024, H=1024.
// Fused-minimal design (round 1):
//   - pack W_in, W_h into MFMA-fragment-ordered bf16 (one 16B coalesced load per lane)
//   - 512 step kernels: gates = x[t]@W_in + h@W_h + b_in + b_h via mfma_f32_16x16x32_bf16
//   - 128 WGs, each owns 8 h-cols (= 32 gate cols: f,i,g,o chunks), 4 waves x 16 batch rows
//   - c state f32 in ws; h ping-pong bf16 in ws; outputs f32 to d_out

#define T_STEPS 512
#define BATCH   64
#define DIM     1024
#define HID     1024
#define G4      4096
#define BH      (BATCH*HID)   // 65536

typedef __attribute__((ext_vector_type(8))) short short8;
typedef __attribute__((ext_vector_type(4))) float f32x4;

__device__ __forceinline__ short f2bs(float f){
  __hip_bfloat16 h = __float2bfloat16(f);
  return *reinterpret_cast<short*>(&h);
}

__device__ __forceinline__ float sigm(float x){ return 1.f/(1.f + __expf(-x)); }
__device__ __forceinline__ float tanh_s(float x){
  float e = __expf(-2.f*fabsf(x));
  float t = (1.f - e)/(1.f + e);
  return copysignf(t, x);
}

// Pack W [1024][4096] f32 -> fragment-ordered bf16.
// Layout: wpk[(((wg*32 + kk)*2 + ct)*64 + lane)*8 + j] = W[kk*32 + (lane>>4)*8 + j][g]
//   g = (q<<10) + wg*8 + (lane&7),  q = ct*2 + ((lane>>3)&1)
__global__ __launch_bounds__(256) void k_pack_w(const float* __restrict__ W, short* __restrict__ wpk){
  int t  = blockIdx.x*256 + threadIdx.x;   // 0..524287 exact
  int l  = t & 63;
  int ct = (t >> 6) & 1;
  int kk = (t >> 7) & 31;
  int wg = t >> 12;
  int kbase = kk*32 + (l >> 4)*8;
  int q = ct*2 + ((l >> 3) & 1);
  int g = (q << 10) + wg*8 + (l & 7);
  short8 v;
  #pragma unroll
  for (int j = 0; j < 8; ++j) v[j] = f2bs(W[(size_t)(kbase + j)*G4 + g]);
  reinterpret_cast<short8*>(wpk)[t] = v;
}

__global__ __launch_bounds__(256) void k_cvt_x(const float* __restrict__ x, short* __restrict__ xb){
  const int n8 = (T_STEPS*BATCH*DIM)/8;
  for (int i = blockIdx.x*256 + threadIdx.x; i < n8; i += gridDim.x*256){
    const float4* p = reinterpret_cast<const float4*>(x) + (size_t)i*2;
    float4 a = p[0], b = p[1];
    short8 v;
    v[0]=f2bs(a.x); v[1]=f2bs(a.y); v[2]=f2bs(a.z); v[3]=f2bs(a.w);
    v[4]=f2bs(b.x); v[5]=f2bs(b.y); v[6]=f2bs(b.z); v[7]=f2bs(b.w);
    reinterpret_cast<short8*>(xb)[i] = v;
  }
}

__global__ __launch_bounds__(256) void k_init(const float* __restrict__ h0, const float* __restrict__ c0,
                                              short* __restrict__ hbuf0, float* __restrict__ cbuf){
  int i = blockIdx.x*256 + threadIdx.x;    // 65536 exact
  hbuf0[i] = f2bs(h0[i]);
  cbuf[i]  = c0[i];
}

// One recurrence step. 128 WGs x 256 threads (4 waves).
// WG wg owns h-cols [wg*8, wg*8+8) -> gate cols {q*1024 + wg*8 + c}.
// Wave w computes batch rows [w*16, w*16+16), two 16x16 accum fragments (ct=0,1).
template<bool XB>
__global__ __launch_bounds__(256) void k_step(
    const short* __restrict__ hprev,       // [64][1024] bf16
    const void*  __restrict__ xt,          // [64][1024] bf16 (XB) or f32
    const short* __restrict__ wi_pk,
    const short* __restrict__ wh_pk,
    const float* __restrict__ b_in, const float* __restrict__ b_h,
    float* __restrict__ cbuf,              // [64][1024] f32 in/out
    float* __restrict__ out_t,             // [64][1024] f32
    short* __restrict__ hnext)             // [64][1024] bf16
{
  const int wg  = blockIdx.x;
  const int tid = threadIdx.x;
  const int l   = tid & 63, w = tid >> 6;
  const int l15 = l & 15, lhi = l >> 4;
  const int arow = w*16 + l15;

  f32x4 acc0 = {0.f,0.f,0.f,0.f}, acc1 = {0.f,0.f,0.f,0.f};

  const short8* hA  = reinterpret_cast<const short8*>(hprev + (size_t)arow*HID);
  const short8* whv = reinterpret_cast<const short8*>(wh_pk) + (size_t)wg*4096;
  const short8* wiv = reinterpret_cast<const short8*>(wi_pk) + (size_t)wg*4096;
  const short8* xA8 = XB ? reinterpret_cast<const short8*>(
                              reinterpret_cast<const short*>(xt) + (size_t)arow*DIM) : nullptr;
  const float4* xA4 = XB ? nullptr : reinterpret_cast<const float4*>(
                              reinterpret_cast<const float*>(xt) + (size_t)arow*DIM);

  #pragma unroll 4
  for (int kk = 0; kk < 32; ++kk){
    // h @ W_h
    short8 ah = hA[kk*4 + lhi];
    short8 b0 = whv[(kk*2 + 0)*64 + l];
    short8 b1 = whv[(kk*2 + 1)*64 + l];
    acc0 = __builtin_amdgcn_mfma_f32_16x16x32_bf16(ah, b0, acc0, 0, 0, 0);
    acc1 = __builtin_amdgcn_mfma_f32_16x16x32_bf16(ah, b1, acc1, 0, 0, 0);
    // x[t] @ W_in
    short8 ax;
    if (XB){
      ax = xA8[kk*4 + lhi];
    } else {
      float4 fa = xA4[kk*8 + lhi*2];
      float4 fb = xA4[kk*8 + lhi*2 + 1];
      ax[0]=f2bs(fa.x); ax[1]=f2bs(fa.y); ax[2]=f2bs(fa.z); ax[3]=f2bs(fa.w);
      ax[4]=f2bs(fb.x); ax[5]=f2bs(fb.y); ax[6]=f2bs(fb.z); ax[7]=f2bs(fb.w);
    }
    short8 d0 = wiv[(kk*2 + 0)*64 + l];
    short8 d1 = wiv[(kk*2 + 1)*64 + l];
    acc0 = __builtin_amdgcn_mfma_f32_16x16x32_bf16(ax, d0, acc0, 0, 0, 0);
    acc1 = __builtin_amdgcn_mfma_f32_16x16x32_bf16(ax, d1, acc1, 0, 0, 0);
  }

  // Epilogue: D layout col = l&15 (N), row = (l>>4)*4 + r (M)  [m89-verified]
  const int q0   = (l >> 3) & 1;       // frag0 chunk: 0=f / 1=i ; frag1: 2=g / 3=o
  const int c    = l & 7;
  const int colh = wg*8 + c;
  const int g0   = (q0 << 10) + colh;
  const int g1   = ((q0 + 2) << 10) + colh;
  const float bias0 = b_in[g0] + b_h[g0];
  const float bias1 = b_in[g1] + b_h[g1];
  const bool alane = (q0 == 0);

  #pragma unroll
  for (int r = 0; r < 4; ++r){
    int row = w*16 + lhi*4 + r;
    float v0 = acc0[r] + bias0;          // f (A-lane) | i (B-lane)
    float v1 = acc1[r] + bias1;          // g (A-lane) | o (B-lane)
    float s0  = sigm(v0);                // σ(f) | σ(i)
    float th1 = tanh_s(v1);              // tanh(g) | -
    float sg1 = sigm(v1);                // -       | σ(o)
    float p_s0  = __shfl_xor(s0, 8, 64); // A-lane receives σ(i)
    float p_sg1 = __shfl_xor(sg1, 8, 64);// A-lane receives σ(o)
    if (alane){
      int idx = row*HID + colh;
      float cold = cbuf[idx];
      float cnew = cold*s0 + p_s0*th1;
      float h    = tanh_s(cnew)*p_sg1;
      cbuf[idx]  = cnew;
      out_t[idx] = h;
      hnext[idx] = f2bs(h);
    }
  }
}

__global__ __launch_bounds__(256) void k_tail(float* __restrict__ out, const float* __restrict__ cbuf){
  int i = blockIdx.x*256 + threadIdx.x;  // 65536 exact
  out[(size_t)T_STEPS*BH + i]      = out[(size_t)(T_STEPS-1)*BH + i];  // h_T
  out[(size_t)T_STEPS*BH + BH + i] = cbuf[i];                          // c_T
}

extern "C" void kernel_launch(void* const* d_in, const int* in_sizes, int n_in,
                              void* d_out, int out_size, void* d_ws, size_t ws_size,
                              hipStream_t stream){
  const float* x  = (const float*)d_in[0];
  const float* h0 = (const float*)d_in[1];
  const float* c0 = (const float*)d_in[2];
  const float* Wi = (const float*)d_in[3];
  const float* bi = (const float*)d_in[4];
  const float* Wh = (const float*)d_in[5];
  const float* bh = (const float*)d_in[6];
  float* out = (float*)d_out;

  char* ws = (char*)d_ws;
  short* wi_pk = (short*)(ws);                                   // 8 MB
  short* wh_pk = (short*)(ws + (size_t)(8u<<20));                // 8 MB
  float* cbuf  = (float*)(ws + (size_t)(16u<<20));               // 256 KB
  short* hbuf0 = (short*)(ws + (size_t)(16u<<20) + (256u<<10));  // 128 KB
  short* hbuf1 = (short*)(ws + (size_t)(16u<<20) + (384u<<10));  // 128 KB
  short* xb    = (short*)(ws + (size_t)(17u<<20));               // 64 MB (optional)
  const bool xbf = ws_size >= ((size_t)(17u<<20) + ((size_t)T_STEPS*BATCH*DIM*2));

  k_pack_w<<<2048, 256, 0, stream>>>(Wi, wi_pk);
  k_pack_w<<<2048, 256, 0, stream>>>(Wh, wh_pk);
  k_init  <<<256, 256, 0, stream>>>(h0, c0, hbuf0, cbuf);
  if (xbf) k_cvt_x<<<4096, 256, 0, stream>>>(x, xb);

  for (int t = 0; t < T_STEPS; ++t){
    const void* xt = xbf ? (const void*)(xb + (size_t)t*BH)
                         : (const void*)(x  + (size_t)t*BH);
    short* hp = (t & 1) ? hbuf1 : hbuf0;
    short* hn = (t & 1) ? hbuf0 : hbuf1;
    if (xbf)
      k_step<true ><<<128, 256, 0, stream>>>(hp, xt, wi_pk, wh_pk, bi, bh,
                                             cbuf, out + (size_t)t*BH, hn);
    else
      k_step<false><<<128, 256, 0, stream>>>(hp, xt, wi_pk, wh_pk, bi, bh,
                                             cbuf, out + (size_t)t*BH, hn);
  }
  k_tail<<<256, 256, 0, stream>>>(out, cbuf);
}

// Round 2
// 10329.561 us; speedup vs baseline: 1.0625x; 1.0625x over previous
//
#include <hip/hip_runtime.h>
#include <hip/hip_bf16.h>

// LSTM T=512, B=64, D=1024, H=1024 — persistent-kernel design (round 2).
// 256 WGs x 512 thr; WG = (cg: 16 h-cols) x (rh: 16 batch rows); wave = K-slice (kp=8).
// Weights live in VGPRs (128/lane) for all 512 steps; grid barrier per step.

#define T_STEPS 512
#define BATCH   64
#define DIM     1024
#define HID     1024
#define G4      4096
#define BH      (BATCH*HID)   // 65536

typedef __attribute__((ext_vector_type(8))) short short8;
typedef __attribute__((ext_vector_type(4))) float f32x4;

__device__ __forceinline__ short f2bs(float f){
  __hip_bfloat16 h = __float2bfloat16(f);
  return *reinterpret_cast<short*>(&h);
}
__device__ __forceinline__ float sigm(float x){ return 1.f/(1.f + __expf(-x)); }
__device__ __forceinline__ float tanh_s(float x){
  float e = __expf(-2.f*fabsf(x));
  float t = (1.f - e)/(1.f + e);
  return copysignf(t, x);
}

// ---- weight pack: W[1024][4096] f32 -> fragment-ordered bf16 ----
// short8 index: (((cg*8 + kp)*4 + kk)*4 + ct)*64 + l
// holds W[kp*128 + kk*32 + (l>>4)*8 + j][ q*1024 + cg*16 + ct*4 + ch ]
//   q = (l>>2)&3, ch = l&3   (B-frag: col16 = l&15, k = (l>>4)*8+j)
__global__ __launch_bounds__(256) void k_pack_w(const float* __restrict__ W, short* __restrict__ wpk){
  int t  = blockIdx.x*256 + threadIdx.x;   // 0..524287 exact
  int l  = t & 63;
  int ct = (t >> 6) & 3;
  int kk = (t >> 8) & 3;
  int kp = (t >> 10) & 7;
  int cg = t >> 13;
  int q  = (l >> 2) & 3, ch = l & 3;
  int g  = (q << 10) + cg*16 + ct*4 + ch;
  int kbase = kp*128 + kk*32 + (l >> 4)*8;
  short8 v;
  #pragma unroll
  for (int j = 0; j < 8; ++j) v[j] = f2bs(W[(size_t)(kbase + j)*G4 + g]);
  reinterpret_cast<short8*>(wpk)[t] = v;
}

__global__ __launch_bounds__(256) void k_cvt_x(const float* __restrict__ x, short* __restrict__ xb){
  const int n8 = (T_STEPS*BATCH*DIM)/8;
  for (int i = blockIdx.x*256 + threadIdx.x; i < n8; i += gridDim.x*256){
    const float4* p = reinterpret_cast<const float4*>(x) + (size_t)i*2;
    float4 a = p[0], b = p[1];
    short8 v;
    v[0]=f2bs(a.x); v[1]=f2bs(a.y); v[2]=f2bs(a.z); v[3]=f2bs(a.w);
    v[4]=f2bs(b.x); v[5]=f2bs(b.y); v[6]=f2bs(b.z); v[7]=f2bs(b.w);
    reinterpret_cast<short8*>(xb)[i] = v;
  }
}

__global__ __launch_bounds__(256) void k_init(const float* __restrict__ h0, short* __restrict__ hb0){
  int i = blockIdx.x*256 + threadIdx.x;    // 65536 exact
  hb0[i] = f2bs(h0[i]);
}

// ---- two-level grid barrier (256 WGs, groups of 32 by wg&7) ----
__device__ __forceinline__ void grid_barrier(unsigned int* bar, int wgid){
  __syncthreads();
  if (threadIdx.x == 0){
    unsigned int g = __hip_atomic_load(bar + 288, __ATOMIC_RELAXED, __HIP_MEMORY_SCOPE_AGENT);
    __threadfence();   // release: flush this XCD's L2 so our stores reach LLC
    int grp = wgid & 7;
    unsigned int prev = __hip_atomic_fetch_add(bar + grp*32, 1u, __ATOMIC_ACQ_REL, __HIP_MEMORY_SCOPE_AGENT);
    if (prev == 31u){
      __hip_atomic_store(bar + grp*32, 0u, __ATOMIC_RELAXED, __HIP_MEMORY_SCOPE_AGENT);
      unsigned int p2 = __hip_atomic_fetch_add(bar + 256, 1u, __ATOMIC_ACQ_REL, __HIP_MEMORY_SCOPE_AGENT);
      if (p2 == 7u){
        __hip_atomic_store(bar + 256, 0u, __ATOMIC_RELAXED, __HIP_MEMORY_SCOPE_AGENT);
        __hip_atomic_fetch_add(bar + 288, 1u, __ATOMIC_RELEASE, __HIP_MEMORY_SCOPE_AGENT);
      }
    }
    while (__hip_atomic_load(bar + 288, __ATOMIC_RELAXED, __HIP_MEMORY_SCOPE_AGENT) == g)
      __builtin_amdgcn_s_sleep(2);
    __threadfence();   // acquire: invalidate L1 + XCD L2 so h loads are fresh
  }
  __syncthreads();
}

// ---- persistent LSTM kernel ----
template<bool XB>
__global__ __launch_bounds__(512, 2) void k_lstm(
    const short* __restrict__ wi_pk, const short* __restrict__ wh_pk,
    const float* __restrict__ b_in, const float* __restrict__ b_h,
    const float* __restrict__ c0,
    const void*  __restrict__ xsrc,
    short* hb0, short* hb1,
    float* __restrict__ out, unsigned int* bar)
{
  const int bid = blockIdx.x;
  const int cg  = bid >> 2, rh = bid & 3;
  const int tid = threadIdx.x;
  const int w   = tid >> 6, l = tid & 63;
  const int kp  = w;
  const int l15 = l & 15, lhi = l >> 4;
  const int q   = (l >> 2) & 3, ch = l & 3;

  __shared__ float red[8][16][64];   // [kp][reg][lane] — coalesced, conflict-free

  // --- preload weight fragments into registers (held for the whole kernel) ---
  short8 wH[4][4], wI[4][4];
  {
    const short8* whv = reinterpret_cast<const short8*>(wh_pk);
    const short8* wiv = reinterpret_cast<const short8*>(wi_pk);
    const int wb = ((cg*8 + kp)*16)*64;
    #pragma unroll
    for (int kk = 0; kk < 4; ++kk)
      #pragma unroll
      for (int ct = 0; ct < 4; ++ct){
        wH[kk][ct] = whv[wb + (kk*4 + ct)*64 + l];
        wI[kk][ct] = wiv[wb + (kk*4 + ct)*64 + l];
      }
  }

  // --- epilogue constants: this wave owns output regs {2w, 2w+1} ---
  const int ctw  = w >> 1;
  const int frb  = (w & 1)*2;
  const int hcol = cg*16 + ctw*4 + ch;
  const int gidx = (q << 10) + hcol;
  const float bias = b_in[gidx] + b_h[gidx];
  const int row0 = rh*16 + lhi*4 + frb;
  float cst[2];
  cst[0] = c0[row0*HID + hcol];
  cst[1] = c0[(row0+1)*HID + hcol];

  // --- A-operand addressing (row = rh*16 + (l&15), k = kp*128 + kk*32 + lhi*8) ---
  const int arow = rh*16 + l15;
  const size_t aoff = (size_t)arow*HID + kp*128 + lhi*8;   // element offset

  const short* xb = (const short*)xsrc;
  const float* xf = (const float*)xsrc;
  short8 xcur[4], xnxt[4];
  if (XB){
    #pragma unroll
    for (int kk = 0; kk < 4; ++kk){
      xcur[kk] = *reinterpret_cast<const short8*>(xb + aoff + kk*32);
      xnxt[kk] = xcur[kk];
    }
  }

  short* hcur = hb0;
  short* hnxt = hb1;

  #pragma unroll 1
  for (int t = 0; t < T_STEPS; ++t){
    // prefetch next step's x (independent of recurrence)
    if (XB && (t + 1 < T_STEPS)){
      const short* xn = xb + (size_t)(t+1)*BH + aoff;
      #pragma unroll
      for (int kk = 0; kk < 4; ++kk)
        xnxt[kk] = *reinterpret_cast<const short8*>(xn + kk*32);
    }

    f32x4 acc[4] = {};
    const short8* hA = reinterpret_cast<const short8*>(hcur + aoff);
    const float4* xA4 = XB ? nullptr
        : reinterpret_cast<const float4*>(xf + (size_t)t*BH + aoff);
    #pragma unroll
    for (int kk = 0; kk < 4; ++kk){
      short8 ah = hA[kk*4];
      short8 ax;
      if (XB){
        ax = xcur[kk];
      } else {
        float4 fa = xA4[kk*8], fb = xA4[kk*8 + 1];
        ax[0]=f2bs(fa.x); ax[1]=f2bs(fa.y); ax[2]=f2bs(fa.z); ax[3]=f2bs(fa.w);
        ax[4]=f2bs(fb.x); ax[5]=f2bs(fb.y); ax[6]=f2bs(fb.z); ax[7]=f2bs(fb.w);
      }
      #pragma unroll
      for (int ct = 0; ct < 4; ++ct){
        acc[ct] = __builtin_amdgcn_mfma_f32_16x16x32_bf16(ah, wH[kk][ct], acc[ct], 0, 0, 0);
        acc[ct] = __builtin_amdgcn_mfma_f32_16x16x32_bf16(ax, wI[kk][ct], acc[ct], 0, 0, 0);
      }
    }

    // --- kp-reduction through LDS ---
    #pragma unroll
    for (int ct = 0; ct < 4; ++ct)
      #pragma unroll
      for (int r = 0; r < 4; ++r)
        red[kp][ct*4 + r][l] = acc[ct][r];
    __syncthreads();
    float v0 = 0.f, v1 = 0.f;
    #pragma unroll
    for (int k2 = 0; k2 < 8; ++k2){
      v0 += red[k2][w*2 + 0][l];
      v1 += red[k2][w*2 + 1][l];
    }

    // --- epilogue: gates -> c,h (this wave: ct=ctw, rows row0,row0+1) ---
    v0 += bias; v1 += bias;
    float a0 = (q == 2) ? tanh_s(v0) : sigm(v0);
    float a1 = (q == 2) ? tanh_s(v1) : sigm(v1);
    float f0_4  = __shfl_xor(a0, 4, 64);   // q^1
    float f0_8  = __shfl_xor(a0, 8, 64);   // q^2
    float f0_12 = __shfl_xor(a0, 12, 64);  // q^3
    float f1_4  = __shfl_xor(a1, 4, 64);
    float f1_8  = __shfl_xor(a1, 8, 64);
    float f1_12 = __shfl_xor(a1, 12, 64);
    if (q == 0){
      const int idx0 = row0*HID + hcol;
      const int idx1 = idx0 + HID;
      cst[0] = cst[0]*a0 + f0_4*f0_8;      // c*σ(f) + σ(i)*tanh(g)
      cst[1] = cst[1]*a1 + f1_4*f1_8;
      float h0v = tanh_s(cst[0])*f0_12;    // tanh(c)*σ(o)
      float h1v = tanh_s(cst[1])*f1_12;
      float* ot = out + (size_t)t*BH;
      ot[idx0] = h0v; ot[idx1] = h1v;
      hnxt[idx0] = f2bs(h0v); hnxt[idx1] = f2bs(h1v);
      if (t == T_STEPS - 1){
        out[(size_t)T_STEPS*BH + idx0] = h0v;
        out[(size_t)T_STEPS*BH + idx1] = h1v;
        out[(size_t)T_STEPS*BH + BH + idx0] = cst[0];
        out[(size_t)T_STEPS*BH + BH + idx1] = cst[1];
      }
    }

    grid_barrier(bar, bid);

    { short* tmp = hcur; hcur = hnxt; hnxt = tmp; }
    if (XB){
      #pragma unroll
      for (int kk = 0; kk < 4; ++kk) xcur[kk] = xnxt[kk];
    }
  }
}

extern "C" void kernel_launch(void* const* d_in, const int* in_sizes, int n_in,
                              void* d_out, int out_size, void* d_ws, size_t ws_size,
                              hipStream_t stream){
  const float* x  = (const float*)d_in[0];
  const float* h0 = (const float*)d_in[1];
  const float* c0 = (const float*)d_in[2];
  const float* Wi = (const float*)d_in[3];
  const float* bi = (const float*)d_in[4];
  const float* Wh = (const float*)d_in[5];
  const float* bh = (const float*)d_in[6];
  float* out = (float*)d_out;

  char* ws = (char*)d_ws;
  short* wi_pk = (short*)(ws);                                   // 8 MB
  short* wh_pk = (short*)(ws + (size_t)(8u<<20));                // 8 MB
  unsigned int* bar = (unsigned int*)(ws + (size_t)(16u<<20));   // 4 KB
  short* hb0 = (short*)(ws + (size_t)(16u<<20) + (4u<<10));      // 128 KB
  short* hb1 = (short*)(ws + (size_t)(16u<<20) + (132u<<10));    // 128 KB
  short* xb  = (short*)(ws + (size_t)(17u<<20));                 // 64 MB (optional)
  const bool xbf = ws_size >= ((size_t)(17u<<20) + ((size_t)T_STEPS*BATCH*DIM*2));

  k_pack_w<<<2048, 256, 0, stream>>>(Wi, wi_pk);
  k_pack_w<<<2048, 256, 0, stream>>>(Wh, wh_pk);
  k_init  <<<256, 256, 0, stream>>>(h0, hb0);
  hipMemsetAsync(bar, 0, 4096, stream);

  if (xbf){
    k_cvt_x<<<4096, 256, 0, stream>>>(x, xb);
    k_lstm<true ><<<256, 512, 0, stream>>>(wi_pk, wh_pk, bi, bh, c0,
                                           (const void*)xb, hb0, hb1, out, bar);
  } else {
    k_lstm<false><<<256, 512, 0, stream>>>(wi_pk, wh_pk, bi, bh, c0,
                                           (const void*)x, hb0, hb1, out, bar);
  }
}

// Round 3
// 3672.131 us; speedup vs baseline: 2.9888x; 2.8130x over previous
//
#include <hip/hip_runtime.h>
#include <hip/hip_bf16.h>

// LSTM T=512, B=64, D=1024, H=1024 — persistent kernel, round 3.
// Changes vs round 2:
//  - fence-free grid barrier: per-WG generation flags, inline-asm sc0/sc1
//    (device-coherent per-access) stores/loads; no buffer_wbl2/inv, no atomic RMW
//  - weights pinned in VGPRs via empty-asm anchors (compiler can't rematerialize)
//  - h exchanged via LLC with bypass (sc0 sc1) ops only; x/out stay L2-cached
//  - out stores + x prefetch moved off the barrier critical path

#define T_STEPS 512
#define BATCH   64
#define DIM     1024
#define HID     1024
#define G4      4096
#define BH      (BATCH*HID)   // 65536

typedef __attribute__((ext_vector_type(8))) short short8;
typedef __attribute__((ext_vector_type(4))) float f32x4;
typedef __attribute__((ext_vector_type(4))) unsigned int u32x4;
typedef __attribute__((ext_vector_type(2))) unsigned int u32x2;

__device__ __forceinline__ short f2bs(float f){
  __hip_bfloat16 h = __float2bfloat16(f);
  return *reinterpret_cast<short*>(&h);
}
__device__ __forceinline__ unsigned short f2bu(float f){
  __hip_bfloat16 h = __float2bfloat16(f);
  return *reinterpret_cast<unsigned short*>(&h);
}
__device__ __forceinline__ float sigm(float x){ return 1.f/(1.f + __expf(-x)); }
__device__ __forceinline__ float tanh_s(float x){
  float e = __expf(-2.f*fabsf(x));
  float t = (1.f - e)/(1.f + e);
  return copysignf(t, x);
}

// ---- weight pack: W[1024][4096] f32 -> fragment-ordered bf16 ----
// short8 index: (((cg*8 + kp)*4 + kk)*4 + ct)*64 + l
// holds W[kp*128 + kk*32 + (l>>4)*8 + j][ q*1024 + cg*16 + ct*4 + ch ]
//   q=(l>>2)&3, ch=l&3
__global__ __launch_bounds__(256) void k_pack_w(const float* __restrict__ W, short* __restrict__ wpk){
  int t  = blockIdx.x*256 + threadIdx.x;   // 0..524287 exact
  int l  = t & 63;
  int ct = (t >> 6) & 3;
  int kk = (t >> 8) & 3;
  int kp = (t >> 10) & 7;
  int cg = t >> 13;
  int q  = (l >> 2) & 3, ch = l & 3;
  int g  = (q << 10) + cg*16 + ct*4 + ch;
  int kbase = kp*128 + kk*32 + (l >> 4)*8;
  short8 v;
  #pragma unroll
  for (int j = 0; j < 8; ++j) v[j] = f2bs(W[(size_t)(kbase + j)*G4 + g]);
  reinterpret_cast<short8*>(wpk)[t] = v;
}

__global__ __launch_bounds__(256) void k_cvt_x(const float* __restrict__ x, short* __restrict__ xb){
  const int n8 = (T_STEPS*BATCH*DIM)/8;
  for (int i = blockIdx.x*256 + threadIdx.x; i < n8; i += gridDim.x*256){
    const float4* p = reinterpret_cast<const float4*>(x) + (size_t)i*2;
    float4 a = p[0], b = p[1];
    short8 v;
    v[0]=f2bs(a.x); v[1]=f2bs(a.y); v[2]=f2bs(a.z); v[3]=f2bs(a.w);
    v[4]=f2bs(b.x); v[5]=f2bs(b.y); v[6]=f2bs(b.z); v[7]=f2bs(b.w);
    reinterpret_cast<short8*>(xb)[i] = v;
  }
}

__global__ __launch_bounds__(256) void k_init(const float* __restrict__ h0, short* __restrict__ hb0){
  int i = blockIdx.x*256 + threadIdx.x;    // 65536 exact
  hb0[i] = f2bs(h0[i]);
}

// ---- persistent LSTM kernel ----
template<bool XB>
__global__ __launch_bounds__(512, 2) void k_lstm(
    const short* __restrict__ wi_pk, const short* __restrict__ wh_pk,
    const float* __restrict__ b_in, const float* __restrict__ b_h,
    const float* __restrict__ c0,
    const void*  __restrict__ xsrc,
    short* hb0, short* hb1,
    float* __restrict__ out, unsigned int* flags)
{
  const int bid = blockIdx.x;
  const int cg  = bid >> 2, rh = bid & 3;
  const int tid = threadIdx.x;
  const int w   = tid >> 6, l = tid & 63;
  const int kp  = w;
  const int l15 = l & 15, lhi = l >> 4;
  const int q   = (l >> 2) & 3, ch = l & 3;

  __shared__ float red[8][16][64];          // 32 KB kp-reduction
  __shared__ unsigned short hsh[16][16];    // 512 B h tile

  // --- weights -> VGPRs, anchored so the compiler can't sink/remat the loads ---
  short8 wH[4][4], wI[4][4];
  {
    const short8* whv = reinterpret_cast<const short8*>(wh_pk);
    const short8* wiv = reinterpret_cast<const short8*>(wi_pk);
    const int wb = ((cg*8 + kp)*16)*64;
    #pragma unroll
    for (int kk = 0; kk < 4; ++kk)
      #pragma unroll
      for (int ct = 0; ct < 4; ++ct){
        wH[kk][ct] = whv[wb + (kk*4 + ct)*64 + l];
        wI[kk][ct] = wiv[wb + (kk*4 + ct)*64 + l];
      }
  }
  #pragma unroll
  for (int kk = 0; kk < 4; ++kk)
    #pragma unroll
    for (int ct = 0; ct < 4; ++ct){
      asm volatile("" : "+v"(wH[kk][ct]));
      asm volatile("" : "+v"(wI[kk][ct]));
    }

  // --- epilogue constants: wave w owns reduce regs {2w, 2w+1} ---
  const int ctw  = w >> 1;
  const int frb  = (w & 1)*2;
  const int hcol = cg*16 + ctw*4 + ch;
  const int gidx = (q << 10) + hcol;
  const float bias = b_in[gidx] + b_h[gidx];
  const int row0 = rh*16 + lhi*4 + frb;
  const int lr   = lhi*4 + frb;       // local row in hsh
  const int lc   = ctw*4 + ch;        // local col in hsh
  float cst0 = c0[row0*HID + hcol];
  float cst1 = c0[(row0+1)*HID + hcol];

  // --- A-operand addressing ---
  const int arow = rh*16 + l15;
  const size_t aoff = (size_t)arow*HID + kp*128 + lhi*8;

  const short* xb = (const short*)xsrc;
  const float* xf = (const float*)xsrc;
  short8 xcur[4];
  if (XB){
    const short* x0 = xb + aoff;
    #pragma unroll
    for (int kk = 0; kk < 4; ++kk)
      xcur[kk] = *reinterpret_cast<const short8*>(x0 + kk*32);
  }

  short* hcur = hb0;
  short* hnxt = hb1;

  #pragma unroll 1
  for (int t = 0; t < T_STEPS; ++t){
    // --- h loads: device-coherent bypass (LLC), 4x dwordx4 + one wait ---
    short8 ah[4];
    {
      const short* hp = hcur + aoff;
      asm volatile(
        "global_load_dwordx4 %0, %4, off sc0 sc1\n\t"
        "global_load_dwordx4 %1, %4, off offset:64 sc0 sc1\n\t"
        "global_load_dwordx4 %2, %4, off offset:128 sc0 sc1\n\t"
        "global_load_dwordx4 %3, %4, off offset:192 sc0 sc1\n\t"
        "s_waitcnt vmcnt(0)"
        : "=&v"(ah[0]), "=&v"(ah[1]), "=&v"(ah[2]), "=&v"(ah[3])
        : "v"(hp) : "memory");
    }

    // --- MFMA: gates partial for this kp slice ---
    f32x4 acc[4] = {};
    const float4* xA4 = XB ? nullptr
        : reinterpret_cast<const float4*>(xf + (size_t)t*BH + aoff);
    #pragma unroll
    for (int kk = 0; kk < 4; ++kk){
      short8 ax;
      if (XB){
        ax = xcur[kk];
      } else {
        float4 fa = xA4[kk*8], fb = xA4[kk*8 + 1];
        ax[0]=f2bs(fa.x); ax[1]=f2bs(fa.y); ax[2]=f2bs(fa.z); ax[3]=f2bs(fa.w);
        ax[4]=f2bs(fb.x); ax[5]=f2bs(fb.y); ax[6]=f2bs(fb.z); ax[7]=f2bs(fb.w);
      }
      #pragma unroll
      for (int ct = 0; ct < 4; ++ct){
        acc[ct] = __builtin_amdgcn_mfma_f32_16x16x32_bf16(ah[kk], wH[kk][ct], acc[ct], 0, 0, 0);
        acc[ct] = __builtin_amdgcn_mfma_f32_16x16x32_bf16(ax,     wI[kk][ct], acc[ct], 0, 0, 0);
      }
    }

    // --- kp-reduction through LDS ---
    #pragma unroll
    for (int ct = 0; ct < 4; ++ct)
      #pragma unroll
      for (int r = 0; r < 4; ++r)
        red[kp][ct*4 + r][l] = acc[ct][r];
    __syncthreads();                                   // S1
    float v0 = 0.f, v1 = 0.f;
    #pragma unroll
    for (int k2 = 0; k2 < 8; ++k2){
      v0 += red[k2][w*2 + 0][l];
      v1 += red[k2][w*2 + 1][l];
    }

    // --- gates -> c,h ---
    v0 += bias; v1 += bias;
    float a0 = (q == 2) ? tanh_s(v0) : sigm(v0);
    float a1 = (q == 2) ? tanh_s(v1) : sigm(v1);
    float f0_4  = __shfl_xor(a0, 4, 64);
    float f0_8  = __shfl_xor(a0, 8, 64);
    float f0_12 = __shfl_xor(a0, 12, 64);
    float f1_4  = __shfl_xor(a1, 4, 64);
    float f1_8  = __shfl_xor(a1, 8, 64);
    float f1_12 = __shfl_xor(a1, 12, 64);
    float h0v = 0.f, h1v = 0.f;
    if (q == 0){
      cst0 = cst0*a0 + f0_4*f0_8;        // c*σ(f) + σ(i)*tanh(g)
      cst1 = cst1*a1 + f1_4*f1_8;
      h0v  = tanh_s(cst0)*f0_12;         // tanh(c)*σ(o)
      h1v  = tanh_s(cst1)*f1_12;
      hsh[lr][lc]     = f2bu(h0v);
      hsh[lr + 1][lc] = f2bu(h1v);
    }
    __syncthreads();                                   // S2: hsh complete

    // --- off-critical-path: out[t] stores (plain cached) ---
    if (q == 0){
      const int idx0 = row0*HID + hcol;
      float* ot = out + (size_t)t*BH;
      ot[idx0] = h0v; ot[idx0 + HID] = h1v;
      if (t == T_STEPS - 1){
        out[(size_t)T_STEPS*BH + idx0]            = h0v;
        out[(size_t)T_STEPS*BH + idx0 + HID]      = h1v;
        out[(size_t)T_STEPS*BH + BH + idx0]       = cst0;
        out[(size_t)T_STEPS*BH + BH + idx0 + HID] = cst1;
      }
    }

    // --- wave 0: h tile -> global (bypass), drain, arrive ---
    if (w == 0){
      const int r = l >> 2, cq = l & 3;
      u32x2 hv = *reinterpret_cast<const u32x2*>(&hsh[r][cq*4]);
      unsigned int* hp2 = reinterpret_cast<unsigned int*>(
          hnxt + (size_t)(rh*16 + r)*HID + cg*16 + cq*4);
      asm volatile(
        "global_store_dwordx2 %0, %1, off sc0 sc1\n\t"
        "s_waitcnt vmcnt(0)"
        :: "v"(hp2), "v"(hv) : "memory");
      if (l == 0){
        unsigned int* fp0 = flags + bid;
        unsigned gv = (unsigned)(t + 1);
        asm volatile("global_store_dword %0, %1, off sc0 sc1"
                     :: "v"(fp0), "v"(gv) : "memory");
      }
    }

    // --- x prefetch for t+1 (overlaps the barrier wait) ---
    if (XB && (t + 1 < T_STEPS)){
      const short* xn = xb + (size_t)(t+1)*BH + aoff;
      #pragma unroll
      for (int kk = 0; kk < 4; ++kk)
        xcur[kk] = *reinterpret_cast<const short8*>(xn + kk*32);
    }

    // --- wave 0: poll all 256 flags (4 per lane, one dwordx4) ---
    if (w == 0){
      const unsigned int* fp = flags + l*4;
      const unsigned gen = (unsigned)(t + 1);
      int ok;
      do {
        u32x4 f;
        asm volatile(
          "global_load_dwordx4 %0, %1, off sc0 sc1\n\t"
          "s_waitcnt vmcnt(0)"
          : "=&v"(f) : "v"(fp) : "memory");
        ok = (f[0] >= gen) && (f[1] >= gen) && (f[2] >= gen) && (f[3] >= gen);
      } while (!__all(ok));
    }
    __syncthreads();                                   // S4

    { short* tmp = hcur; hcur = hnxt; hnxt = tmp; }
  }
}

extern "C" void kernel_launch(void* const* d_in, const int* in_sizes, int n_in,
                              void* d_out, int out_size, void* d_ws, size_t ws_size,
                              hipStream_t stream){
  const float* x  = (const float*)d_in[0];
  const float* h0 = (const float*)d_in[1];
  const float* c0 = (const float*)d_in[2];
  const float* Wi = (const float*)d_in[3];
  const float* bi = (const float*)d_in[4];
  const float* Wh = (const float*)d_in[5];
  const float* bh = (const float*)d_in[6];
  float* out = (float*)d_out;

  char* ws = (char*)d_ws;
  short* wi_pk = (short*)(ws);                                   // 8 MB
  short* wh_pk = (short*)(ws + (size_t)(8u<<20));                // 8 MB
  unsigned int* flags = (unsigned int*)(ws + (size_t)(16u<<20)); // 1 KB (4 KB reserved)
  short* hb0 = (short*)(ws + (size_t)(16u<<20) + (4u<<10));      // 128 KB
  short* hb1 = (short*)(ws + (size_t)(16u<<20) + (132u<<10));    // 128 KB
  short* xb  = (short*)(ws + (size_t)(17u<<20));                 // 64 MB (optional)
  const bool xbf = ws_size >= ((size_t)(17u<<20) + ((size_t)T_STEPS*BATCH*DIM*2));

  k_pack_w<<<2048, 256, 0, stream>>>(Wi, wi_pk);
  k_pack_w<<<2048, 256, 0, stream>>>(Wh, wh_pk);
  k_init  <<<256, 256, 0, stream>>>(h0, hb0);
  hipMemsetAsync(flags, 0, 4096, stream);

  if (xbf){
    k_cvt_x<<<4096, 256, 0, stream>>>(x, xb);
    k_lstm<true ><<<256, 512, 0, stream>>>(wi_pk, wh_pk, bi, bh, c0,
                                           (const void*)xb, hb0, hb1, out, flags);
  } else {
    k_lstm<false><<<256, 512, 0, stream>>>(wi_pk, wh_pk, bi, bh, c0,
                                           (const void*)x, hb0, hb1, out, flags);
  }
}